// Round 9
// baseline (273.995 us; speedup 1.0000x reference)
//
#include <hip/hip_runtime.h>
#include <stdint.h>

typedef __attribute__((ext_vector_type(4))) int i32x4;

#define N_FRAMES 16386
#define D_DIM    1024
#define O_DIM    2048
#define L_CTX    3
#define K_DIM    3072   // D_DIM * L_CTX
#define T_DIM    16384  // N_FRAMES - L_CTX + 1
#define NKT      48     // K_DIM / 64  (64-byte K-tiles)

// workspace byte offsets
#define WS_MM     0u
#define WS_PARAMS 64u
#define WS_CO     256u
#define WS_S      16384u
#define WS_CT     98304u
#define WS_QW     262144u
#define WS_QX     8388608u

struct Params {
  float w_scale, in_scale, cscale;
  int   w_zp, in_zp, konst;
};

typedef __attribute__((address_space(3))) void       lds_void;
typedef const __attribute__((address_space(1))) void gbl_void;

__device__ __forceinline__ unsigned flip_f(float f) {
  unsigned u = __float_as_uint(f);
  return (u & 0x80000000u) ? ~u : (u | 0x80000000u);
}
__device__ __forceinline__ float unflip_f(unsigned v) {
  unsigned u = (v & 0x80000000u) ? (v ^ 0x80000000u) : ~v;
  return __uint_as_float(u);
}

__global__ void init_kernel(unsigned* mm) {
  mm[0] = 0xFFFFFFFFu;
  mm[1] = 0u;
}

__global__ __launch_bounds__(256) void wminmax_kernel(const float4* __restrict__ w,
                                                      unsigned* mm, int n4) {
  unsigned lmin = 0xFFFFFFFFu, lmax = 0u;
  for (int i = blockIdx.x * blockDim.x + threadIdx.x; i < n4; i += gridDim.x * blockDim.x) {
    float4 v = w[i];
    unsigned a = flip_f(v.x), b = flip_f(v.y), c = flip_f(v.z), d = flip_f(v.w);
    lmin = min(lmin, min(min(a, b), min(c, d)));
    lmax = max(lmax, max(max(a, b), max(c, d)));
  }
#pragma unroll
  for (int off = 32; off > 0; off >>= 1) {
    lmin = min(lmin, (unsigned)__shfl_xor((int)lmin, off, 64));
    lmax = max(lmax, (unsigned)__shfl_xor((int)lmax, off, 64));
  }
  if ((threadIdx.x & 63) == 0) {
    atomicMin(&mm[0], lmin);
    atomicMax(&mm[1], lmax);
  }
}

__global__ void params_kernel(const unsigned* __restrict__ mm,
                              const float* __restrict__ in_min,
                              const float* __restrict__ in_max,
                              Params* __restrict__ p) {
  float wmin = unflip_f(mm[0]);
  float wmax = unflip_f(mm[1]);
  float ws = (wmax - wmin) / 254.0f;
  float wz = -127.0f - wmin / ws;
  wz = fminf(fmaxf(wz, -127.0f), 127.0f);
  int wzp = (int)wz;
  float imin = *in_min, imax = *in_max;
  float is = (imax - imin) / 254.0f;
  float iz = -127.0f - imin / is;
  iz = fminf(fmaxf(iz, -127.0f), 127.0f);
  int izp = (int)iz;
  p->w_scale = ws; p->in_scale = is; p->cscale = is * ws;
  p->w_zp = wzp;   p->in_zp = izp;
  p->konst = K_DIM * wzp * izp;
}

__global__ __launch_bounds__(256) void quantw_kernel(
    const float* __restrict__ w, const float* __restrict__ bias,
    const Params* __restrict__ p, int8_t* __restrict__ qw,
    int* __restrict__ co, float* __restrict__ dq, float* __restrict__ bias_out) {
  const int o = blockIdx.x;
  const float ws = p->w_scale;
  const float zpf = (float)p->w_zp;
  const float* wrow = w + (size_t)o * K_DIM;
  float* dqrow = dq + (size_t)o * K_DIM;
  int8_t* qrow = qw + (size_t)o * K_DIM;
  int sum = 0;
#pragma unroll
  for (int pass = 0; pass < 3; ++pass) {
    const int k = (pass << 10) + (threadIdx.x << 2);
    float4 v = *(const float4*)(wrow + k);
    int8_t c0 = (int8_t)(int)rintf(v.x / ws + zpf);
    int8_t c1 = (int8_t)(int)rintf(v.y / ws + zpf);
    int8_t c2 = (int8_t)(int)rintf(v.z / ws + zpf);
    int8_t c3 = (int8_t)(int)rintf(v.w / ws + zpf);
    sum += (int)c0 + (int)c1 + (int)c2 + (int)c3;
    unsigned packed = (unsigned)(uint8_t)c0 | ((unsigned)(uint8_t)c1 << 8)
                    | ((unsigned)(uint8_t)c2 << 16) | ((unsigned)(uint8_t)c3 << 24);
    *(unsigned*)(qrow + k) = packed;
    float4 d;
    d.x = ((float)c0 - zpf) * ws;
    d.y = ((float)c1 - zpf) * ws;
    d.z = ((float)c2 - zpf) * ws;
    d.w = ((float)c3 - zpf) * ws;
    *(float4*)(dqrow + k) = d;
  }
  __shared__ int red[4];
#pragma unroll
  for (int off = 32; off > 0; off >>= 1) sum += __shfl_xor(sum, off, 64);
  if ((threadIdx.x & 63) == 0) red[threadIdx.x >> 6] = sum;
  __syncthreads();
  if (threadIdx.x == 0) {
    int tot = red[0] + red[1] + red[2] + red[3];
    co[o] = -p->in_zp * tot;
    bias_out[o] = bias[o];
  }
}

__global__ __launch_bounds__(256) void quantx_kernel(
    const float* __restrict__ x, const Params* __restrict__ p,
    int8_t* __restrict__ qx, int* __restrict__ s) {
  const int n = blockIdx.x;
  const float is = p->in_scale;
  const float zpf = (float)p->in_zp;
  const float4 v = *((const float4*)(x + (size_t)n * D_DIM) + threadIdx.x);
  int8_t c0 = (int8_t)(int)rintf(v.x / is + zpf);
  int8_t c1 = (int8_t)(int)rintf(v.y / is + zpf);
  int8_t c2 = (int8_t)(int)rintf(v.z / is + zpf);
  int8_t c3 = (int8_t)(int)rintf(v.w / is + zpf);
  unsigned packed = (unsigned)(uint8_t)c0 | ((unsigned)(uint8_t)c1 << 8)
                  | ((unsigned)(uint8_t)c2 << 16) | ((unsigned)(uint8_t)c3 << 24);
  ((unsigned*)(qx + (size_t)n * D_DIM))[threadIdx.x] = packed;
  int sum = (int)c0 + (int)c1 + (int)c2 + (int)c3;
  __shared__ int red[4];
#pragma unroll
  for (int off = 32; off > 0; off >>= 1) sum += __shfl_xor(sum, off, 64);
  if ((threadIdx.x & 63) == 0) red[threadIdx.x >> 6] = sum;
  __syncthreads();
  if (threadIdx.x == 0) s[n] = red[0] + red[1] + red[2] + red[3];
}

__global__ __launch_bounds__(256) void ct_kernel(const int* __restrict__ s,
                                                 const Params* __restrict__ p,
                                                 int* __restrict__ ct) {
  const int t = blockIdx.x * blockDim.x + threadIdx.x;
  if (t < T_DIM) ct[t] = p->konst - p->w_zp * (s[t] + s[t + 1] + s[t + 2]);
}

// int8 NT GEMM — OCCUPANCY build: 128x128 tile, 4 waves (2x2, per-wave 64x64),
// 64B K-tiles, TRIPLE-buffered LDS (3x16KB = 48KB) -> 3 blocks/CU = 3 waves/SIMD
// from 3 INDEPENDENT blocks (cross-block latency hiding). Race-safe ledger:
// stage(j+2) only after the barrier certifying frags(j-1) drained block-wide.
// Swizzle: 64B rows, s(row) = (row ^ (row>>2)) & 3 applied to 16B chunks.
__global__ __launch_bounds__(256, 3) void gemm_kernel(
    const int8_t* __restrict__ qx, const int8_t* __restrict__ qw,
    const int* __restrict__ co, const int* __restrict__ ct,
    const float* __restrict__ bias, const Params* __restrict__ p,
    float* __restrict__ out) {
  __shared__ int8_t A_lds[3][8192];   // [buf][row*64 + chunk*16], 128 rows
  __shared__ int8_t B_lds[3][8192];

  const int bid = blockIdx.x;
  const int tn = bid & 15;   // XCD j hosts tn in {j, j+8}: B panels 768KB L2-resident
  const int tm = bid >> 4;
  const int m0 = tm << 7, n0 = tn << 7;
  const int tid = threadIdx.x;
  const int lane = tid & 63, wave = tid >> 6;
  const int wm = wave >> 1, wn = wave & 1;   // 2x2 wave grid, per-wave 64x64
  const int lr = lane & 15, kg = lane >> 4;

  // staging: per wave-event 1KB = 16 rows x 64B; lane l -> row l>>2, chunk l&3.
  // source chunk pre-swizzled with s(localrow)= ((l>>2)&3)^((l>>4)&3) so linear
  // LDS dest holds swizzled layout (both-sides involution, rule #21).
  const int lrow = lane >> 2;
  const int lsw  = (((lane & 3) ^ (lrow & 3) ^ ((lrow >> 2) & 3)) << 4);
  const int8_t* srcA = qx + (size_t)(m0 + (wave << 5) + lrow) * D_DIM + lsw;
  const int8_t* srcB = qw + (size_t)(n0 + (wave << 5) + lrow) * K_DIM + lsw;

  // fragment read: row = base + lr; phys chunk = kg ^ (row&3) ^ ((row>>2)&3)
  // = kg ^ (lr&3) ^ ((lr>>2)&3)  (bases are multiples of 16)
  const int fragc = ((kg ^ (lane & 3) ^ ((lane >> 2) & 3)) << 4) & 0x30;
  // note: (lane&3)... lr==lane&15 so lr&3==lane&3, lr>>2==(lane>>2)&3 for lane<16;
  // for all lanes use lr explicitly:
  const int fc = ((kg ^ (lr & 3) ^ ((lr >> 2) & 3)) << 4);
  (void)fragc;

  i32x4 aE[4], aO[4], bE[4], bO[4];
  i32x4 acc[4][4] = {};

  // stage K-tile kt into LDS[buf]: 2 A-events + 2 B-events per wave
  auto stage = [&](int buf, int kt) {
#pragma unroll
    for (int e = 0; e < 2; ++e) {
      __builtin_amdgcn_global_load_lds(
          (gbl_void*)(srcA + (size_t)(e << 4) * D_DIM + (kt << 6)),
          (lds_void*)(&A_lds[buf][(wave << 11) + (e << 10)]), 16, 0, 0);
      __builtin_amdgcn_global_load_lds(
          (gbl_void*)(srcB + (size_t)(e << 4) * K_DIM + (kt << 6)),
          (lds_void*)(&B_lds[buf][(wave << 11) + (e << 10)]), 16, 0, 0);
    }
  };
  auto readF = [&](i32x4 (&a)[4], i32x4 (&b)[4], int buf) {
#pragma unroll
    for (int m = 0; m < 4; ++m)
      a[m] = *(const i32x4*)&A_lds[buf][(((wm << 6) + (m << 4) + lr) << 6) + fc];
#pragma unroll
    for (int n = 0; n < 4; ++n)
      b[n] = *(const i32x4*)&B_lds[buf][(((wn << 6) + (n << 4) + lr) << 6) + fc];
  };

  // prologue: stage tiles 0,1; drain tile 0 (tile 1's 4 events fly); read frags(0)
  stage(0, 0);
  stage(1, 1);
  asm volatile("s_waitcnt vmcnt(4)" ::: "memory");
  __builtin_amdgcn_s_barrier();
  readF(aE, bE, 0);

#pragma unroll 2
  for (int j = 0; j < NKT; ++j) {
    const int pj = j & 1;
    if (j + 1 < NKT) {
      asm volatile("s_waitcnt vmcnt(0)" ::: "memory");   // stage(j+1) landed
    }
    __builtin_amdgcn_s_barrier();                        // frags(j-1) drained block-wide
    if (j + 2 < NKT) stage((j + 2) % 3, j + 2);          // buf held tile j-1: free
    if (j + 1 < NKT) {
      if (pj) readF(aE, bE, (j + 1) % 3);
      else    readF(aO, bO, (j + 1) % 3);
      asm volatile("s_waitcnt lgkmcnt(8)" ::: "memory"); // frags(j) complete; new 8 fly
    } else {
      asm volatile("s_waitcnt lgkmcnt(0)" ::: "memory");
    }
    __builtin_amdgcn_s_setprio(1);
    if (pj == 0) {
#pragma unroll
      for (int m = 0; m < 4; ++m)
#pragma unroll
        for (int n = 0; n < 4; ++n)
          acc[m][n] = __builtin_amdgcn_mfma_i32_16x16x64_i8(aE[m], bE[n], acc[m][n], 0, 0, 0);
    } else {
#pragma unroll
      for (int m = 0; m < 4; ++m)
#pragma unroll
        for (int n = 0; n < 4; ++n)
          acc[m][n] = __builtin_amdgcn_mfma_i32_16x16x64_i8(aO[m], bO[n], acc[m][n], 0, 0, 0);
    }
    __builtin_amdgcn_s_setprio(0);
  }

  // epilogue: dequant + zero-point correction + bias
  const float cscale = p->cscale;
  int   cov[4];
  float bov[4];
#pragma unroll
  for (int n = 0; n < 4; ++n) {
    const int o_ = n0 + (wn << 6) + (n << 4) + lr;
    cov[n] = co[o_];
    bov[n] = bias[o_];
  }
#pragma unroll
  for (int m = 0; m < 4; ++m) {
    const int tbase = m0 + (wm << 6) + (m << 4) + (kg << 2);
    int ctv[4];
#pragma unroll
    for (int r = 0; r < 4; ++r) ctv[r] = ct[tbase + r];
#pragma unroll
    for (int n = 0; n < 4; ++n) {
      const int o_ = n0 + (wn << 6) + (n << 4) + lr;
#pragma unroll
      for (int r = 0; r < 4; ++r) {
        out[(size_t)(tbase + r) * O_DIM + o_] =
            (float)(acc[m][n][r] + cov[n] + ctv[r]) * cscale + bov[n];
      }
    }
  }
}

extern "C" void kernel_launch(void* const* d_in, const int* in_sizes, int n_in,
                              void* d_out, int out_size, void* d_ws, size_t ws_size,
                              hipStream_t stream) {
  const float* x      = (const float*)d_in[0];
  const float* w      = (const float*)d_in[1];
  const float* bias   = (const float*)d_in[2];
  const float* in_min = (const float*)d_in[3];
  const float* in_max = (const float*)d_in[4];
  float* out = (float*)d_out;

  uint8_t* ws = (uint8_t*)d_ws;
  unsigned* mm = (unsigned*)(ws + WS_MM);
  Params*   prm = (Params*)(ws + WS_PARAMS);
  int*      co = (int*)(ws + WS_CO);
  int*      s  = (int*)(ws + WS_S);
  int*      ct = (int*)(ws + WS_CT);
  int8_t*   qw = (int8_t*)(ws + WS_QW);
  int8_t*   qx = (int8_t*)(ws + WS_QX);

  float* dq_out   = out + (size_t)T_DIM * O_DIM;
  float* bias_out = dq_out + (size_t)O_DIM * K_DIM;

  init_kernel<<<1, 1, 0, stream>>>(mm);
  wminmax_kernel<<<512, 256, 0, stream>>>((const float4*)w, mm, O_DIM * K_DIM / 4);
  params_kernel<<<1, 1, 0, stream>>>(mm, in_min, in_max, prm);
  quantw_kernel<<<O_DIM, 256, 0, stream>>>(w, bias, prm, qw, co, dq_out, bias_out);
  quantx_kernel<<<N_FRAMES, 256, 0, stream>>>(x, prm, qx, s);
  ct_kernel<<<T_DIM / 256, 256, 0, stream>>>(s, prm, ct);
  gemm_kernel<<<(T_DIM / 128) * (O_DIM / 128), 256, 0, stream>>>(qx, qw, co, ct, bias, prm, out);
}

// Round 10
// 151.997 us; speedup vs baseline: 1.8026x; 1.8026x over previous
//
#include <hip/hip_runtime.h>
#include <stdint.h>

typedef __attribute__((ext_vector_type(4))) int i32x4;

#define N_FRAMES 16386
#define D_DIM    1024
#define O_DIM    2048
#define L_CTX    3
#define K_DIM    3072   // D_DIM * L_CTX
#define T_DIM    16384  // N_FRAMES - L_CTX + 1
#define NKT      24     // K_DIM / 128  (128-byte K-tiles)

// workspace byte offsets
#define WS_PART   0u        // 512 x uint2 flipped {min,max} partials
#define WS_PARAMS 8192u
#define WS_CO     16384u    // O_DIM int32
#define WS_S      32768u    // N_FRAMES int32
#define WS_QW     262144u
#define WS_QX     8388608u

struct Params {
  float w_scale, in_scale, cscale;
  int   w_zp, in_zp, konst;
};

typedef __attribute__((address_space(3))) void       lds_void;
typedef const __attribute__((address_space(1))) void gbl_void;

__device__ __forceinline__ unsigned flip_f(float f) {
  unsigned u = __float_as_uint(f);
  return (u & 0x80000000u) ? ~u : (u | 0x80000000u);
}
__device__ __forceinline__ float unflip_f(unsigned v) {
  unsigned u = (v & 0x80000000u) ? (v ^ 0x80000000u) : ~v;
  return __uint_as_float(u);
}

// grid must be exactly 512 blocks; block b writes partials[b] = {min,max} (flipped)
__global__ __launch_bounds__(256) void wminmax_kernel(const float4* __restrict__ w,
                                                      uint2* __restrict__ part, int n4) {
  unsigned lmin = 0xFFFFFFFFu, lmax = 0u;
  for (int i = blockIdx.x * blockDim.x + threadIdx.x; i < n4; i += gridDim.x * blockDim.x) {
    float4 v = w[i];
    unsigned a = flip_f(v.x), b = flip_f(v.y), c = flip_f(v.z), d = flip_f(v.w);
    lmin = min(lmin, min(min(a, b), min(c, d)));
    lmax = max(lmax, max(max(a, b), max(c, d)));
  }
#pragma unroll
  for (int off = 32; off > 0; off >>= 1) {
    lmin = min(lmin, (unsigned)__shfl_xor((int)lmin, off, 64));
    lmax = max(lmax, (unsigned)__shfl_xor((int)lmax, off, 64));
  }
  __shared__ unsigned rmn[4], rmx[4];
  const int wv = threadIdx.x >> 6;
  if ((threadIdx.x & 63) == 0) { rmn[wv] = lmin; rmx[wv] = lmax; }
  __syncthreads();
  if (threadIdx.x == 0) {
    unsigned mn = min(min(rmn[0], rmn[1]), min(rmn[2], rmn[3]));
    unsigned mx = max(max(rmx[0], rmx[1]), max(rmx[2], rmx[3]));
    part[blockIdx.x] = make_uint2(mn, mx);
  }
}

// reduce 512 partials -> Params
__global__ __launch_bounds__(256) void params_kernel(const uint2* __restrict__ part,
                                                     const float* __restrict__ in_min,
                                                     const float* __restrict__ in_max,
                                                     Params* __restrict__ p) {
  const int t = threadIdx.x;
  uint2 a = part[t], b = part[t + 256];
  unsigned mn = min(a.x, b.x), mx = max(a.y, b.y);
#pragma unroll
  for (int off = 32; off > 0; off >>= 1) {
    mn = min(mn, (unsigned)__shfl_xor((int)mn, off, 64));
    mx = max(mx, (unsigned)__shfl_xor((int)mx, off, 64));
  }
  __shared__ unsigned rmn[4], rmx[4];
  const int wv = t >> 6;
  if ((t & 63) == 0) { rmn[wv] = mn; rmx[wv] = mx; }
  __syncthreads();
  if (t == 0) {
    float wmin = unflip_f(min(min(rmn[0], rmn[1]), min(rmn[2], rmn[3])));
    float wmax = unflip_f(max(max(rmx[0], rmx[1]), max(rmx[2], rmx[3])));
    float ws = (wmax - wmin) / 254.0f;
    float wz = -127.0f - wmin / ws;
    wz = fminf(fmaxf(wz, -127.0f), 127.0f);
    int wzp = (int)wz;  // trunc toward zero, matches jnp.trunc->int
    float imin = *in_min, imax = *in_max;
    float is = (imax - imin) / 254.0f;
    float iz = -127.0f - imin / is;
    iz = fminf(fmaxf(iz, -127.0f), 127.0f);
    int izp = (int)iz;
    p->w_scale = ws; p->in_scale = is; p->cscale = is * ws;
    p->w_zp = wzp;   p->in_zp = izp;
    p->konst = K_DIM * wzp * izp;
  }
}

__global__ __launch_bounds__(256) void quantw_kernel(
    const float* __restrict__ w, const float* __restrict__ bias,
    const Params* __restrict__ p, int8_t* __restrict__ qw,
    int* __restrict__ co, float* __restrict__ dq, float* __restrict__ bias_out) {
  const int o = blockIdx.x;
  const float ws = p->w_scale;
  const float zpf = (float)p->w_zp;
  const float* wrow = w + (size_t)o * K_DIM;
  float* dqrow = dq + (size_t)o * K_DIM;
  int8_t* qrow = qw + (size_t)o * K_DIM;
  int sum = 0;
#pragma unroll
  for (int pass = 0; pass < 3; ++pass) {
    const int k = (pass << 10) + (threadIdx.x << 2);
    float4 v = *(const float4*)(wrow + k);
    int8_t c0 = (int8_t)(int)rintf(v.x / ws + zpf);
    int8_t c1 = (int8_t)(int)rintf(v.y / ws + zpf);
    int8_t c2 = (int8_t)(int)rintf(v.z / ws + zpf);
    int8_t c3 = (int8_t)(int)rintf(v.w / ws + zpf);
    sum += (int)c0 + (int)c1 + (int)c2 + (int)c3;
    unsigned packed = (unsigned)(uint8_t)c0 | ((unsigned)(uint8_t)c1 << 8)
                    | ((unsigned)(uint8_t)c2 << 16) | ((unsigned)(uint8_t)c3 << 24);
    *(unsigned*)(qrow + k) = packed;
    float4 d;
    d.x = ((float)c0 - zpf) * ws;
    d.y = ((float)c1 - zpf) * ws;
    d.z = ((float)c2 - zpf) * ws;
    d.w = ((float)c3 - zpf) * ws;
    *(float4*)(dqrow + k) = d;
  }
  __shared__ int red[4];
#pragma unroll
  for (int off = 32; off > 0; off >>= 1) sum += __shfl_xor(sum, off, 64);
  if ((threadIdx.x & 63) == 0) red[threadIdx.x >> 6] = sum;
  __syncthreads();
  if (threadIdx.x == 0) {
    int tot = red[0] + red[1] + red[2] + red[3];
    co[o] = -p->in_zp * tot;
    bias_out[o] = bias[o];
  }
}

__global__ __launch_bounds__(256) void quantx_kernel(
    const float* __restrict__ x, const Params* __restrict__ p,
    int8_t* __restrict__ qx, int* __restrict__ s) {
  const int n = blockIdx.x;
  const float is = p->in_scale;
  const float zpf = (float)p->in_zp;
  const float4 v = *((const float4*)(x + (size_t)n * D_DIM) + threadIdx.x);
  int8_t c0 = (int8_t)(int)rintf(v.x / is + zpf);
  int8_t c1 = (int8_t)(int)rintf(v.y / is + zpf);
  int8_t c2 = (int8_t)(int)rintf(v.z / is + zpf);
  int8_t c3 = (int8_t)(int)rintf(v.w / is + zpf);
  unsigned packed = (unsigned)(uint8_t)c0 | ((unsigned)(uint8_t)c1 << 8)
                  | ((unsigned)(uint8_t)c2 << 16) | ((unsigned)(uint8_t)c3 << 24);
  ((unsigned*)(qx + (size_t)n * D_DIM))[threadIdx.x] = packed;
  int sum = (int)c0 + (int)c1 + (int)c2 + (int)c3;
  __shared__ int red[4];
#pragma unroll
  for (int off = 32; off > 0; off >>= 1) sum += __shfl_xor(sum, off, 64);
  if ((threadIdx.x & 63) == 0) red[threadIdx.x >> 6] = sum;
  __syncthreads();
  if (threadIdx.x == 0) s[n] = red[0] + red[1] + red[2] + red[3];
}

// int8 NT GEMM, 256x256 tile, 128B K-tiles, 8 waves.  (R4 schedule, proven best)
// 2 phases per K-tile: {12 ds_read (next ks-half) | bar | lgkmcnt(12) counted |
// [stage 8 gloads, P1 only] | setprio | 32 MFMA | setprio | [vmcnt(0), P0 only,
// 1 K-tile slack] | bar}.  ct computed inline in epilogue from s[].
__global__ __launch_bounds__(512, 2) void gemm_kernel(
    const int8_t* __restrict__ qx, const int8_t* __restrict__ qw,
    const int* __restrict__ co, const int* __restrict__ s,
    const float* __restrict__ bias, const Params* __restrict__ p,
    float* __restrict__ out) {
  __shared__ int8_t A_lds[2][256 * 128];   // 32 KB per buf
  __shared__ int8_t B_lds[2][256 * 128];

  const int bid = blockIdx.x;
  const int tn = bid & 7;   // XCD-local n-tile: B panel L2-resident per XCD
  const int tm = bid >> 3;
  const int m0 = tm << 8, n0 = tn << 8;
  const int tid = threadIdx.x;
  const int lane = tid & 63, wave = tid >> 6;
  const int wm = wave >> 2, wn = wave & 3;   // 2x4 wave grid, per-wave 128x64
  const int lr = lane & 15, kg = lane >> 4;
  const int lr7 = lane & 7;

  // staging: thread t covers row t>>3, lds chunk t&7; source chunk pre-swizzled
  // with ^(row&7) so linear LDS dest holds swizzled layout.
  const int st_row = tid >> 3;
  const int st_sc  = ((tid & 7) ^ (st_row & 7)) << 4;
  const int8_t* qxa = qx + (size_t)(m0 + st_row) * D_DIM + st_sc;
  const int8_t* qwb = qw + (size_t)(n0 + st_row) * K_DIM + st_sc;

  // fragment read: phys chunk = ((ks<<2)|kg) ^ (row&7); row&7 == lr7
  const int c0 = (kg ^ lr7) << 4;            // ks=0; ks=1 -> c0 ^ 64
  const int arow = ((wm << 7) + lr) << 7;    // A row base byte
  const int brow = ((wn << 6) + lr) << 7;

  i32x4 a[8][2], b[4][2];
  i32x4 acc[8][4] = {};

  auto stageA = [&](int buf, int kt) {
    const int8_t* sp = qxa + (kt << 7);
#pragma unroll
    for (int j = 0; j < 4; ++j)
      __builtin_amdgcn_global_load_lds((gbl_void*)(sp + (size_t)(j << 6) * D_DIM),
          (lds_void*)(&A_lds[buf][(j << 13) + (wave << 10)]), 16, 0, 0);
  };
  auto stageB = [&](int buf, int kt) {
    const int8_t* sp = qwb + (kt << 7);
#pragma unroll
    for (int j = 0; j < 4; ++j)
      __builtin_amdgcn_global_load_lds((gbl_void*)(sp + (size_t)(j << 6) * K_DIM),
          (lds_void*)(&B_lds[buf][(j << 13) + (wave << 10)]), 16, 0, 0);
  };
  // 12 ds_read_b128 of one ks-half of tile's fragments from LDS buffer bf
  auto read_half = [&](int bf, int ks) {
#pragma unroll
    for (int m = 0; m < 8; ++m)
      a[m][ks] = *(const i32x4*)&A_lds[bf][arow + (m << 11) + (c0 ^ (ks << 6))];
#pragma unroll
    for (int n = 0; n < 4; ++n)
      b[n][ks] = *(const i32x4*)&B_lds[bf][brow + (n << 11) + (c0 ^ (ks << 6))];
  };

  // prologue: stage tiles 0,1; wait tile 0 (tile 1's 8 loads stay in flight);
  // read ks=0 half of tile 0.
  stageA(0, 0); stageB(0, 0);
  stageA(1, 1); stageB(1, 1);
  asm volatile("s_waitcnt vmcnt(8)" ::: "memory");
  __builtin_amdgcn_s_barrier();
  read_half(0, 0);

  for (int kt = 0; kt < NKT; ++kt) {
    const int buf = kt & 1, nxt = buf ^ 1;

    // ---- P0: ds_read ks=1 half (tile kt, buf); MFMA ks=0 ----
    read_half(buf, 1);
    __builtin_amdgcn_s_barrier();
    asm volatile("s_waitcnt lgkmcnt(12)" ::: "memory");  // prev 12 reads done; ours fly
    __builtin_amdgcn_s_setprio(1);
#pragma unroll
    for (int m = 0; m < 8; ++m)
#pragma unroll
      for (int n = 0; n < 4; ++n)
        acc[m][n] = __builtin_amdgcn_mfma_i32_16x16x64_i8(a[m][0], b[n][0], acc[m][n], 0, 0, 0);
    __builtin_amdgcn_s_setprio(0);
    // drain stage(kt+1) (issued a full K-tile ago -> landed; near-free wait)
    asm volatile("s_waitcnt vmcnt(0)" ::: "memory");
    __builtin_amdgcn_s_barrier();

    // ---- P1: ds_read ks=0 half (tile kt+1, nxt); stage kt+2 -> buf; MFMA ks=1 ----
    if (kt + 1 < NKT) read_half(nxt, 0);
    __builtin_amdgcn_s_barrier();
    if (kt + 1 < NKT) {
      asm volatile("s_waitcnt lgkmcnt(12)" ::: "memory");  // P0's 12 done; ours fly
    } else {
      asm volatile("s_waitcnt lgkmcnt(0)" ::: "memory");   // last iter: drain P0's reads
    }
    if (kt + 2 < NKT) { stageA(buf, kt + 2); stageB(buf, kt + 2); }  // buf reads drained above
    __builtin_amdgcn_s_setprio(1);
#pragma unroll
    for (int m = 0; m < 8; ++m)
#pragma unroll
      for (int n = 0; n < 4; ++n)
        acc[m][n] = __builtin_amdgcn_mfma_i32_16x16x64_i8(a[m][1], b[n][1], acc[m][n], 0, 0, 0);
    __builtin_amdgcn_s_setprio(0);
    __builtin_amdgcn_s_barrier();
  }

  // epilogue: dequant + zero-point correction (ct inline from s[]) + bias
  const float cscale = p->cscale;
  const int   wzp    = p->w_zp;
  const int   konst  = p->konst;
  int   cov[4];
  float bov[4];
#pragma unroll
  for (int n = 0; n < 4; ++n) {
    const int o_ = n0 + (wn << 6) + (n << 4) + lr;
    cov[n] = co[o_];
    bov[n] = bias[o_];
  }
#pragma unroll
  for (int m = 0; m < 8; ++m) {
    const int tbase = m0 + (wm << 7) + (m << 4) + (kg << 2);
    int sv[6];
#pragma unroll
    for (int r = 0; r < 6; ++r) sv[r] = s[tbase + r];
    int ctv[4];
#pragma unroll
    for (int r = 0; r < 4; ++r) ctv[r] = konst - wzp * (sv[r] + sv[r + 1] + sv[r + 2]);
#pragma unroll
    for (int n = 0; n < 4; ++n) {
      const int o_ = n0 + (wn << 6) + (n << 4) + lr;
#pragma unroll
      for (int r = 0; r < 4; ++r) {
        out[(size_t)(tbase + r) * O_DIM + o_] =
            (float)(acc[m][n][r] + cov[n] + ctv[r]) * cscale + bov[n];
      }
    }
  }
}

extern "C" void kernel_launch(void* const* d_in, const int* in_sizes, int n_in,
                              void* d_out, int out_size, void* d_ws, size_t ws_size,
                              hipStream_t stream) {
  const float* x      = (const float*)d_in[0];
  const float* w      = (const float*)d_in[1];
  const float* bias   = (const float*)d_in[2];
  const float* in_min = (const float*)d_in[3];
  const float* in_max = (const float*)d_in[4];
  float* out = (float*)d_out;

  uint8_t* ws = (uint8_t*)d_ws;
  uint2*    part = (uint2*)(ws + WS_PART);
  Params*   prm  = (Params*)(ws + WS_PARAMS);
  int*      co   = (int*)(ws + WS_CO);
  int*      s    = (int*)(ws + WS_S);
  int8_t*   qw   = (int8_t*)(ws + WS_QW);
  int8_t*   qx   = (int8_t*)(ws + WS_QX);

  float* dq_out   = out + (size_t)T_DIM * O_DIM;
  float* bias_out = dq_out + (size_t)O_DIM * K_DIM;

  wminmax_kernel<<<512, 256, 0, stream>>>((const float4*)w, part, O_DIM * K_DIM / 4);
  params_kernel<<<1, 256, 0, stream>>>(part, in_min, in_max, prm);
  quantw_kernel<<<O_DIM, 256, 0, stream>>>(w, bias, prm, qw, co, dq_out, bias_out);
  quantx_kernel<<<N_FRAMES, 256, 0, stream>>>(x, prm, qx, s);
  gemm_kernel<<<(T_DIM / 256) * (O_DIM / 256), 512, 0, stream>>>(qx, qw, co, s, bias, prm, out);
}

// Round 12
// 135.808 us; speedup vs baseline: 2.0175x; 1.1192x over previous
//
#include <hip/hip_runtime.h>
#include <stdint.h>

typedef __attribute__((ext_vector_type(4))) int i32x4;

#define N_FRAMES 16386
#define D_DIM    1024
#define O_DIM    2048
#define L_CTX    3
#define K_DIM    3072   // D_DIM * L_CTX
#define T_DIM    16384  // N_FRAMES - L_CTX + 1
#define NKT      24     // K_DIM / 128  (128-byte K-tiles)

// workspace byte offsets
#define WS_PART   0u        // 512 x uint2 flipped {min,max} partials
#define WS_PARAMS 8192u
#define WS_CO     16384u    // O_DIM int32
#define WS_S      32768u    // N_FRAMES int32
#define WS_QW     262144u
#define WS_QX     8388608u

struct Params {
  float w_scale, in_scale, cscale;
  int   w_zp, in_zp, konst;
};

typedef __attribute__((address_space(3))) void       lds_void;
typedef const __attribute__((address_space(1))) void gbl_void;

__device__ __forceinline__ unsigned flip_f(float f) {
  unsigned u = __float_as_uint(f);
  return (u & 0x80000000u) ? ~u : (u | 0x80000000u);
}
__device__ __forceinline__ float unflip_f(unsigned v) {
  unsigned u = (v & 0x80000000u) ? (v ^ 0x80000000u) : ~v;
  return __uint_as_float(u);
}

// grid must be exactly 512 blocks; block b writes partials[b] = {min,max} (flipped)
__global__ __launch_bounds__(256) void wminmax_kernel(const float4* __restrict__ w,
                                                      uint2* __restrict__ part, int n4) {
  unsigned lmin = 0xFFFFFFFFu, lmax = 0u;
  for (int i = blockIdx.x * blockDim.x + threadIdx.x; i < n4; i += gridDim.x * blockDim.x) {
    float4 v = w[i];
    unsigned a = flip_f(v.x), b = flip_f(v.y), c = flip_f(v.z), d = flip_f(v.w);
    lmin = min(lmin, min(min(a, b), min(c, d)));
    lmax = max(lmax, max(max(a, b), max(c, d)));
  }
#pragma unroll
  for (int off = 32; off > 0; off >>= 1) {
    lmin = min(lmin, (unsigned)__shfl_xor((int)lmin, off, 64));
    lmax = max(lmax, (unsigned)__shfl_xor((int)lmax, off, 64));
  }
  __shared__ unsigned rmn[4], rmx[4];
  const int wv = threadIdx.x >> 6;
  if ((threadIdx.x & 63) == 0) { rmn[wv] = lmin; rmx[wv] = lmax; }
  __syncthreads();
  if (threadIdx.x == 0) {
    unsigned mn = min(min(rmn[0], rmn[1]), min(rmn[2], rmn[3]));
    unsigned mx = max(max(rmx[0], rmx[1]), max(rmx[2], rmx[3]));
    part[blockIdx.x] = make_uint2(mn, mx);
  }
}

// reduce 512 partials -> Params
__global__ __launch_bounds__(256) void params_kernel(const uint2* __restrict__ part,
                                                     const float* __restrict__ in_min,
                                                     const float* __restrict__ in_max,
                                                     Params* __restrict__ p) {
  const int t = threadIdx.x;
  uint2 a = part[t], b = part[t + 256];
  unsigned mn = min(a.x, b.x), mx = max(a.y, b.y);
#pragma unroll
  for (int off = 32; off > 0; off >>= 1) {
    mn = min(mn, (unsigned)__shfl_xor((int)mn, off, 64));
    mx = max(mx, (unsigned)__shfl_xor((int)mx, off, 64));
  }
  __shared__ unsigned rmn[4], rmx[4];
  const int wv = t >> 6;
  if ((t & 63) == 0) { rmn[wv] = mn; rmx[wv] = mx; }
  __syncthreads();
  if (t == 0) {
    float wmin = unflip_f(min(min(rmn[0], rmn[1]), min(rmn[2], rmn[3])));
    float wmax = unflip_f(max(max(rmx[0], rmx[1]), max(rmx[2], rmx[3])));
    float ws = (wmax - wmin) / 254.0f;
    float wz = -127.0f - wmin / ws;
    wz = fminf(fmaxf(wz, -127.0f), 127.0f);
    int wzp = (int)wz;  // trunc toward zero, matches jnp.trunc->int
    float imin = *in_min, imax = *in_max;
    float is = (imax - imin) / 254.0f;
    float iz = -127.0f - imin / is;
    iz = fminf(fmaxf(iz, -127.0f), 127.0f);
    int izp = (int)iz;
    p->w_scale = ws; p->in_scale = is; p->cscale = is * ws;
    p->w_zp = wzp;   p->in_zp = izp;
    p->konst = K_DIM * wzp * izp;
  }
}

__global__ __launch_bounds__(256) void quantw_kernel(
    const float* __restrict__ w, const float* __restrict__ bias,
    const Params* __restrict__ p, int8_t* __restrict__ qw,
    int* __restrict__ co, float* __restrict__ dq, float* __restrict__ bias_out) {
  const int o = blockIdx.x;
  const float ws = p->w_scale;
  const float zpf = (float)p->w_zp;
  const float* wrow = w + (size_t)o * K_DIM;
  float* dqrow = dq + (size_t)o * K_DIM;
  int8_t* qrow = qw + (size_t)o * K_DIM;
  int sum = 0;
#pragma unroll
  for (int pass = 0; pass < 3; ++pass) {
    const int k = (pass << 10) + (threadIdx.x << 2);
    float4 v = *(const float4*)(wrow + k);
    int8_t c0 = (int8_t)(int)rintf(v.x / ws + zpf);
    int8_t c1 = (int8_t)(int)rintf(v.y / ws + zpf);
    int8_t c2 = (int8_t)(int)rintf(v.z / ws + zpf);
    int8_t c3 = (int8_t)(int)rintf(v.w / ws + zpf);
    sum += (int)c0 + (int)c1 + (int)c2 + (int)c3;
    unsigned packed = (unsigned)(uint8_t)c0 | ((unsigned)(uint8_t)c1 << 8)
                    | ((unsigned)(uint8_t)c2 << 16) | ((unsigned)(uint8_t)c3 << 24);
    *(unsigned*)(qrow + k) = packed;
    float4 d;
    d.x = ((float)c0 - zpf) * ws;
    d.y = ((float)c1 - zpf) * ws;
    d.z = ((float)c2 - zpf) * ws;
    d.w = ((float)c3 - zpf) * ws;
    *(float4*)(dqrow + k) = d;
  }
  __shared__ int red[4];
#pragma unroll
  for (int off = 32; off > 0; off >>= 1) sum += __shfl_xor(sum, off, 64);
  if ((threadIdx.x & 63) == 0) red[threadIdx.x >> 6] = sum;
  __syncthreads();
  if (threadIdx.x == 0) {
    int tot = red[0] + red[1] + red[2] + red[3];
    co[o] = -p->in_zp * tot;
    bias_out[o] = bias[o];
  }
}

__global__ __launch_bounds__(256) void quantx_kernel(
    const float* __restrict__ x, const Params* __restrict__ p,
    int8_t* __restrict__ qx, int* __restrict__ s) {
  const int n = blockIdx.x;
  const float is = p->in_scale;
  const float zpf = (float)p->in_zp;
  const float4 v = *((const float4*)(x + (size_t)n * D_DIM) + threadIdx.x);
  int8_t c0 = (int8_t)(int)rintf(v.x / is + zpf);
  int8_t c1 = (int8_t)(int)rintf(v.y / is + zpf);
  int8_t c2 = (int8_t)(int)rintf(v.z / is + zpf);
  int8_t c3 = (int8_t)(int)rintf(v.w / is + zpf);
  unsigned packed = (unsigned)(uint8_t)c0 | ((unsigned)(uint8_t)c1 << 8)
                  | ((unsigned)(uint8_t)c2 << 16) | ((unsigned)(uint8_t)c3 << 24);
  ((unsigned*)(qx + (size_t)n * D_DIM))[threadIdx.x] = packed;
  int sum = (int)c0 + (int)c1 + (int)c2 + (int)c3;
  __shared__ int red[4];
#pragma unroll
  for (int off = 32; off > 0; off >>= 1) sum += __shfl_xor(sum, off, 64);
  if ((threadIdx.x & 63) == 0) red[threadIdx.x >> 6] = sum;
  __syncthreads();
  if (threadIdx.x == 0) s[n] = red[0] + red[1] + red[2] + red[3];
}

// int8 NT GEMM, 256x256 tile, 128B K-tiles, 8 waves.
// ONE-phase K-tile, barrier-certified (race-free version of R11):
//  {lgkmcnt(0) [frags(kt) done] | setprio | 64 MFMA | setprio |
//   vmcnt(0) [own stage(kt+1) landed] |
//   s_barrier [block-wide: stage(kt+1) landed AND frags(kt) reads drained] |
//   24 ds_read frags(kt+1) from nxt | stage(kt+2) -> buf}.
// 1 barrier + 1 vmcnt + 1 lgkm per K-tile (R4 had 4 bar + 3 gates).
__global__ __launch_bounds__(512, 2) void gemm_kernel(
    const int8_t* __restrict__ qx, const int8_t* __restrict__ qw,
    const int* __restrict__ co, const int* __restrict__ s,
    const float* __restrict__ bias, const Params* __restrict__ p,
    float* __restrict__ out) {
  __shared__ int8_t A_lds[2][256 * 128];   // 32 KB per buf
  __shared__ int8_t B_lds[2][256 * 128];

  const int bid = blockIdx.x;
  const int tn = bid & 7;   // XCD-local n-tile: B panel L2-resident per XCD
  const int tm = bid >> 3;
  const int m0 = tm << 8, n0 = tn << 8;
  const int tid = threadIdx.x;
  const int lane = tid & 63, wave = tid >> 6;
  const int wm = wave >> 2, wn = wave & 3;   // 2x4 wave grid, per-wave 128x64
  const int lr = lane & 15, kg = lane >> 4;
  const int lr7 = lane & 7;

  // staging: thread t covers row t>>3, lds chunk t&7; source chunk pre-swizzled
  // with ^(row&7) so linear LDS dest holds swizzled layout.
  const int st_row = tid >> 3;
  const int st_sc  = ((tid & 7) ^ (st_row & 7)) << 4;
  const int8_t* qxa = qx + (size_t)(m0 + st_row) * D_DIM + st_sc;
  const int8_t* qwb = qw + (size_t)(n0 + st_row) * K_DIM + st_sc;

  // fragment read: phys chunk = ((ks<<2)|kg) ^ (row&7); row&7 == lr7
  const int c0 = (kg ^ lr7) << 4;            // ks=0; ks=1 -> c0 ^ 64
  const int arow = ((wm << 7) + lr) << 7;    // A row base byte
  const int brow = ((wn << 6) + lr) << 7;

  i32x4 a[8][2], b[4][2];
  i32x4 acc[8][4] = {};

  auto stageA = [&](int buf, int kt) {
    const int8_t* sp = qxa + (kt << 7);
#pragma unroll
    for (int j = 0; j < 4; ++j)
      __builtin_amdgcn_global_load_lds((gbl_void*)(sp + (size_t)(j << 6) * D_DIM),
          (lds_void*)(&A_lds[buf][(j << 13) + (wave << 10)]), 16, 0, 0);
  };
  auto stageB = [&](int buf, int kt) {
    const int8_t* sp = qwb + (kt << 7);
#pragma unroll
    for (int j = 0; j < 4; ++j)
      __builtin_amdgcn_global_load_lds((gbl_void*)(sp + (size_t)(j << 6) * K_DIM),
          (lds_void*)(&B_lds[buf][(j << 13) + (wave << 10)]), 16, 0, 0);
  };
  // 24 ds_read_b128: full fragment set for the tile in LDS buffer bf
  auto read_full = [&](int bf) {
#pragma unroll
    for (int ks = 0; ks < 2; ++ks) {
#pragma unroll
      for (int m = 0; m < 8; ++m)
        a[m][ks] = *(const i32x4*)&A_lds[bf][arow + (m << 11) + (c0 ^ (ks << 6))];
#pragma unroll
      for (int n = 0; n < 4; ++n)
        b[n][ks] = *(const i32x4*)&B_lds[bf][brow + (n << 11) + (c0 ^ (ks << 6))];
    }
  };

  // prologue: stage tiles 0,1; wait tile 0 (tile 1's 8 loads stay in flight);
  // read full fragment set of tile 0.
  stageA(0, 0); stageB(0, 0);
  stageA(1, 1); stageB(1, 1);
  asm volatile("s_waitcnt vmcnt(8)" ::: "memory");
  __builtin_amdgcn_s_barrier();
  read_full(0);

  for (int kt = 0; kt < NKT; ++kt) {
    const int buf = kt & 1, nxt = buf ^ 1;

    asm volatile("s_waitcnt lgkmcnt(0)" ::: "memory");   // frags(kt) complete (own reads)
    __builtin_amdgcn_s_setprio(1);
#pragma unroll
    for (int m = 0; m < 8; ++m)
#pragma unroll
      for (int n = 0; n < 4; ++n)
#pragma unroll
        for (int ks = 0; ks < 2; ++ks)
          acc[m][n] = __builtin_amdgcn_mfma_i32_16x16x64_i8(a[m][ks], b[n][ks], acc[m][n], 0, 0, 0);
    __builtin_amdgcn_s_setprio(0);

    if (kt + 1 < NKT) {
      asm volatile("s_waitcnt vmcnt(0)" ::: "memory");   // own stage(kt+1) loads landed
      __builtin_amdgcn_s_barrier();                      // block-wide: stage(kt+1) landed
                                                         // AND all frags(kt) reads drained
      read_full(nxt);                                    // tile kt+1; gated next iter
      if (kt + 2 < NKT) { stageA(buf, kt + 2); stageB(buf, kt + 2); }  // buf certified free
    }
  }

  // epilogue: dequant + zero-point correction (ct inline from s[]) + bias
  const float cscale = p->cscale;
  const int   wzp    = p->w_zp;
  const int   konst  = p->konst;
  int   cov[4];
  float bov[4];
#pragma unroll
  for (int n = 0; n < 4; ++n) {
    const int o_ = n0 + (wn << 6) + (n << 4) + lr;
    cov[n] = co[o_];
    bov[n] = bias[o_];
  }
#pragma unroll
  for (int m = 0; m < 8; ++m) {
    const int tbase = m0 + (wm << 7) + (m << 4) + (kg << 2);
    int sv[6];
#pragma unroll
    for (int r = 0; r < 6; ++r) sv[r] = s[tbase + r];
    int ctv[4];
#pragma unroll
    for (int r = 0; r < 4; ++r) ctv[r] = konst - wzp * (sv[r] + sv[r + 1] + sv[r + 2]);
#pragma unroll
    for (int n = 0; n < 4; ++n) {
      const int o_ = n0 + (wn << 6) + (n << 4) + lr;
#pragma unroll
      for (int r = 0; r < 4; ++r) {
        out[(size_t)(tbase + r) * O_DIM + o_] =
            (float)(acc[m][n][r] + cov[n] + ctv[r]) * cscale + bov[n];
      }
    }
  }
}

extern "C" void kernel_launch(void* const* d_in, const int* in_sizes, int n_in,
                              void* d_out, int out_size, void* d_ws, size_t ws_size,
                              hipStream_t stream) {
  const float* x      = (const float*)d_in[0];
  const float* w      = (const float*)d_in[1];
  const float* bias   = (const float*)d_in[2];
  const float* in_min = (const float*)d_in[3];
  const float* in_max = (const float*)d_in[4];
  float* out = (float*)d_out;

  uint8_t* ws = (uint8_t*)d_ws;
  uint2*    part = (uint2*)(ws + WS_PART);
  Params*   prm  = (Params*)(ws + WS_PARAMS);
  int*      co   = (int*)(ws + WS_CO);
  int*      s    = (int*)(ws + WS_S);
  int8_t*   qw   = (int8_t*)(ws + WS_QW);
  int8_t*   qx   = (int8_t*)(ws + WS_QX);

  float* dq_out   = out + (size_t)T_DIM * O_DIM;
  float* bias_out = dq_out + (size_t)O_DIM * K_DIM;

  wminmax_kernel<<<512, 256, 0, stream>>>((const float4*)w, part, O_DIM * K_DIM / 4);
  params_kernel<<<1, 256, 0, stream>>>(part, in_min, in_max, prm);
  quantw_kernel<<<O_DIM, 256, 0, stream>>>(w, bias, prm, qw, co, dq_out, bias_out);
  quantx_kernel<<<N_FRAMES, 256, 0, stream>>>(x, prm, qx, s);
  gemm_kernel<<<(T_DIM / 256) * (O_DIM / 256), 512, 0, stream>>>(qx, qw, co, s, bias, prm, out);
}